// Round 15
// baseline (372.772 us; speedup 1.0000x reference)
//
#include <hip/hip_runtime.h>
#include <hip/hip_bf16.h>
#include <math.h>

#define N_NODES 50000
#define N_EDGES 1600000
#define N_GRAPHS 64
#define NB 391             // dst buckets of 128 nodes: b = dst >> 7
#define NBLK 256           // partition blocks
#define CHUNK 6250         // edges per partition block (256*6250 = 1.6M exactly)
#define ROW_STRIDE 80      // per-node adjacency capacity (multiple of 8)
#define SENT 50047         // sentinel node: al[SENT] = -1e30 -> exp(score) = 0
#define PB_NODES 32        // pool: nodes per block (4 waves x 8-node runs)

typedef unsigned int u32;
typedef __attribute__((ext_vector_type(8))) __bf16 bf16x8;
typedef __attribute__((ext_vector_type(4))) float f32x4;

__device__ __forceinline__ float bcf(u32 u) { return __builtin_bit_cast(float, u); }

template <int CTRL>
__device__ __forceinline__ float dpp_add(float v) {
    int r = __builtin_amdgcn_update_dpp(0, __builtin_bit_cast(int, v), CTRL, 0xF, 0xF, true);
    return v + __builtin_bit_cast(float, r);
}

__device__ __forceinline__ u32 pack_bf16x2(float lo, float hi) {
    unsigned short l = __builtin_bit_cast(unsigned short, __float2bfloat16(lo));
    unsigned short h = __builtin_bit_cast(unsigned short, __float2bfloat16(hi));
    return (u32)l | ((u32)h << 16);
}

// ---------------------------------------------------------------------------
// W -> MFMA-B-fragment layout, hi/lo residual split (device helper; rides the
// count grid as blocks 256/257).
// ---------------------------------------------------------------------------
__device__ __forceinline__ void conv_w_dev(
    int K, const float* __restrict__ Wl, const float* __restrict__ Wr,
    u32* __restrict__ wfHi, u32* __restrict__ wfLo) {
    const int KO = K / 32;
    for (int idx = threadIdx.x; idx < KO * 8 * 64; idx += 256) {
        const int L = idx & 63;
        const int tile = idx >> 6;
        const int ko = tile >> 3, nt = tile & 7;
        const int c = nt * 16 + (L & 15);
        u32 hi[4], lo[4];
        float hv[8], lv[8];
#pragma unroll
        for (int i = 0; i < 8; ++i) {
            const int k = ko * 32 + (L >> 4) * 8 + i;
            const float wv = (c < 64) ? Wl[k * 64 + c] : Wr[k * 64 + (c - 64)];
            const __hip_bfloat16 h = __float2bfloat16(wv);
            hv[i] = wv;
            lv[i] = wv - __bfloat162float(h);
        }
#pragma unroll
        for (int i = 0; i < 4; ++i) {
            hi[i] = pack_bf16x2(hv[2 * i], hv[2 * i + 1]);
            lo[i] = pack_bf16x2(lv[2 * i], lv[2 * i + 1]);
        }
        *(uint4*)(wfHi + (size_t)idx * 4) = make_uint4(hi[0], hi[1], hi[2], hi[3]);
        *(uint4*)(wfLo + (size_t)idx * 4) = make_uint4(lo[0], lo[1], lo[2], lo[3]);
    }
}

// Blocks 0..255: per-chunk dst-bucket histogram -> countsRM[blk][bucket].
// Blocks 256/257: W-fragment conversion (independent riders).
__global__ __launch_bounds__(256) void count_kernel(
    const int* __restrict__ ei, int* __restrict__ countsRM,
    const float* __restrict__ Wl1, const float* __restrict__ Wr1,
    const float* __restrict__ Wl2, const float* __restrict__ Wr2,
    u32* __restrict__ wf1hi, u32* __restrict__ wf1lo,
    u32* __restrict__ wf2hi, u32* __restrict__ wf2lo) {
    if (blockIdx.x == 256) { conv_w_dev(128, Wl1, Wr1, wf1hi, wf1lo); return; }
    if (blockIdx.x == 257) { conv_w_dev(64, Wl2, Wr2, wf2hi, wf2lo); return; }
    __shared__ int h[NB];
    const int t = threadIdx.x;
    for (int k = t; k < NB; k += 256) h[k] = 0;
    __syncthreads();
    const int base = blockIdx.x * CHUNK;
    for (int e = base + t; e < base + CHUNK; e += 256)
        atomicAdd(&h[ei[N_EDGES + e] >> 7], 1);
    __syncthreads();
    for (int k = t; k < NB; k += 256) countsRM[blockIdx.x * NB + k] = h[k];
}

// One block per bucket: parallel exclusive scan over the 256 block counts.
__global__ __launch_bounds__(256) void scan_bucket(
    const int* __restrict__ countsRM, int* __restrict__ scanT,
    int* __restrict__ totals) {
    __shared__ int tmp[256];
    const int b = blockIdx.x;
    const int t = threadIdx.x;
    const int v0 = countsRM[t * NB + b];
    tmp[t] = v0;
    __syncthreads();
    for (int off = 1; off < 256; off <<= 1) {
        int v = (t >= off) ? tmp[t - off] : 0;
        __syncthreads();
        tmp[t] += v;
        __syncthreads();
    }
    scanT[b * 256 + t] = tmp[t] - v0;   // exclusive
    if (t == 255) totals[b] = tmp[t];
}

__global__ __launch_bounds__(512) void scan_total(
    const int* __restrict__ totals, int* __restrict__ bucketBase,
    float* __restrict__ alb) {
    __shared__ int tmp[512];
    const int t = threadIdx.x;
    const int v0 = (t < NB) ? totals[t] : 0;
    tmp[t] = v0;
    __syncthreads();
    for (int off = 1; off < 512; off <<= 1) {
        int v = (t >= off) ? tmp[t - off] : 0;
        __syncthreads();
        tmp[t] += v;
        __syncthreads();
    }
    if (t < NB) bucketBase[t] = tmp[t] - v0;
    if (t == NB - 1) bucketBase[NB] = tmp[t];
    // L1-layout sentinel (indices 100094/100095; gemm writes only < 100000)
    if (t == 0) { alb[(size_t)SENT * 2] = -1e30f; alb[(size_t)SENT * 2 + 1] = -1e30f; }
}

// ---------------------------------------------------------------------------
// MFMA dense transform: [xl|xr] = x @ [Wl|Wr] via bf16 16x16x32 MFMA, W hi/lo
// residual (f32 acc -> W-rounding negligible). AF32: A is f32, packed to bf16
// in-register (layer 1); else A is packed-bf16 rows (h1 for layer 2).
// Epilogue through padded LDS tile: xl->bf16 pack, xr->f32, att-dots al/ar.
// FUSE_SCATTER: blocks >= gemmBlocks run the radix scatter (LDS aliased).
// K==64: al pre-summed; block 0 sets L2 sentinel.
// ---------------------------------------------------------------------------
template <int K, bool AF32, bool FUSE_SCATTER>
__global__ __launch_bounds__(256) void gemm_mfma(
    const float* __restrict__ xF, const u32* __restrict__ xB,
    const u32* __restrict__ wfHi, const u32* __restrict__ wfLo,
    const float* __restrict__ att,
    u32* __restrict__ xlb, float* __restrict__ xr,
    float* __restrict__ alb, float* __restrict__ arb,
    const int* __restrict__ ei, const int* __restrict__ scanT,
    const int* __restrict__ bb, int* __restrict__ sortedE, int gemmBlocks) {
    __shared__ float Ct[64][129];   // +1 pad: column reads conflict-free
    __shared__ float alq[64][4];
    const int t = threadIdx.x;
    if (FUSE_SCATTER && blockIdx.x >= gemmBlocks) {
        int* cursor = (int*)&Ct[0][0];
        const int b = blockIdx.x - gemmBlocks;
        for (int k = t; k < NB; k += 256)
            cursor[k] = bb[k] + scanT[k * 256 + b];
        __syncthreads();
        const int base = b * CHUNK;
        for (int e = base + t; e < base + CHUNK; e += 256) {
            const int s = ei[e];
            const int d = ei[N_EDGES + e];
            const int idx = atomicAdd(&cursor[d >> 7], 1);   // LDS atomic
            sortedE[idx] = (s << 7) | (d & 127);
        }
        return;
    }
    const int KO = K / 32;
    const int lane = t & 63;
    const int w = __builtin_amdgcn_readfirstlane(t >> 6);
    const int quad = lane >> 4;
    const int m16 = lane & 15;
    const int base = blockIdx.x * 64;
    const int arow = base + w * 16 + m16;
    const int rowc = arow < N_NODES ? arow : N_NODES - 1;   // clamp (safe loads)

    f32x4 acc[8];
    const f32x4 zz = {0.f, 0.f, 0.f, 0.f};
#pragma unroll
    for (int i = 0; i < 8; ++i) acc[i] = zz;

#pragma unroll
    for (int ko = 0; ko < KO; ++ko) {
        bf16x8 af;
        if (AF32) {
            const float* ap = xF + (size_t)rowc * K + ko * 32 + quad * 8;
            const float4 a0 = *(const float4*)ap;
            const float4 a1 = *(const float4*)(ap + 4);
            af = __builtin_bit_cast(bf16x8, make_uint4(
                pack_bf16x2(a0.x, a0.y), pack_bf16x2(a0.z, a0.w),
                pack_bf16x2(a1.x, a1.y), pack_bf16x2(a1.z, a1.w)));
        } else {
            af = __builtin_bit_cast(bf16x8,
                *(const uint4*)(xB + ((size_t)rowc * K + ko * 32 + quad * 8) / 2));
        }
#pragma unroll
        for (int nt = 0; nt < 8; ++nt) {
            const uint4 bh = *(const uint4*)(wfHi + (size_t)((ko * 8 + nt) * 64 + lane) * 4);
            acc[nt] = __builtin_amdgcn_mfma_f32_16x16x32_bf16(
                af, __builtin_bit_cast(bf16x8, bh), acc[nt], 0, 0, 0);
        }
#pragma unroll
        for (int nt = 0; nt < 8; ++nt) {
            const uint4 bl = *(const uint4*)(wfLo + (size_t)((ko * 8 + nt) * 64 + lane) * 4);
            acc[nt] = __builtin_amdgcn_mfma_f32_16x16x32_bf16(
                af, __builtin_bit_cast(bf16x8, bl), acc[nt], 0, 0, 0);
        }
    }
    // C/D layout: col = lane&15, row = quad*4 + reg   [verified mapping]
#pragma unroll
    for (int nt = 0; nt < 8; ++nt)
#pragma unroll
        for (int r = 0; r < 4; ++r)
            Ct[w * 16 + quad * 4 + r][nt * 16 + m16] = acc[nt][r];
    __syncthreads();

    const int node = t & 63;
    const int q = t >> 6;          // quarter: 0,1 -> xl cols; 2,3 -> xr cols
    const int n = base + node;
    float av = 0.f;
    if (n < N_NODES) {
        if (q < 2) {
            u32 pk[16];
#pragma unroll
            for (int j = 0; j < 32; j += 2) {
                const float v0 = Ct[node][q * 32 + j];
                const float v1 = Ct[node][q * 32 + j + 1];
                av = fmaf(att[q * 32 + j], v0, av);
                av = fmaf(att[q * 32 + j + 1], v1, av);
                pk[j >> 1] = pack_bf16x2(v0, v1);
            }
            uint4* dst = (uint4*)(xlb + (size_t)n * 32 + q * 16);
#pragma unroll
            for (int j = 0; j < 4; ++j)
                dst[j] = make_uint4(pk[j * 4], pk[j * 4 + 1], pk[j * 4 + 2], pk[j * 4 + 3]);
        } else {
            const int cb = (q - 2) * 32;
#pragma unroll
            for (int j = 0; j < 32; j += 4) {
                float4 v = {Ct[node][64 + cb + j], Ct[node][64 + cb + j + 1],
                            Ct[node][64 + cb + j + 2], Ct[node][64 + cb + j + 3]};
                av = fmaf(att[cb + j], v.x, av);
                av = fmaf(att[cb + j + 1], v.y, av);
                av = fmaf(att[cb + j + 2], v.z, av);
                av = fmaf(att[cb + j + 3], v.w, av);
                *(float4*)(xr + (size_t)n * 64 + cb + j) = v;
            }
        }
    }
    alq[node][q] = av;
    __syncthreads();
    if (t < 64 && base + t < N_NODES) {
        const int nn = base + t;
        if (K == 128) {
            alb[(size_t)nn * 2] = alq[t][0];
            alb[(size_t)nn * 2 + 1] = alq[t][1];
        } else {
            alb[nn] = alq[t][0] + alq[t][1];   // pre-summed for L2
        }
        arb[(size_t)nn * 2] = alq[t][2];
        arb[(size_t)nn * 2 + 1] = alq[t][3];
    }
    if (K == 64 && blockIdx.x == 0 && t == 0) alb[SENT] = -1e30f;   // L2 sentinel
}

// Expand: self-loop pre-seeded as entry 0; rows padded to x8 with SENT.
__global__ __launch_bounds__(256) void expand_kernel(
    const int* __restrict__ bucketBase, const int* __restrict__ sortedE,
    int* __restrict__ deg, int* __restrict__ rows) {
    __shared__ int ldeg[128];
    const int b = blockIdx.x;
    const int t = threadIdx.x;
    const int node_base = b * 128;
    if (t < 128) {
        const int n = node_base + t;
        ldeg[t] = 1;
        if (n < N_NODES) rows[(size_t)n * ROW_STRIDE] = n;   // self loop
    }
    __syncthreads();
    const int beg = bucketBase[b];
    const int end = bucketBase[b + 1];
    for (int i = beg + t; i < end; i += 256) {
        const int en = sortedE[i];
        const int ld = en & 127;
        const int pos = atomicAdd(&ldeg[ld], 1);
        if (pos < ROW_STRIDE) rows[(size_t)(node_base + ld) * ROW_STRIDE + pos] = en >> 7;
    }
    __syncthreads();
    if (t < 128) {
        const int n = node_base + t;
        if (n < N_NODES) {
            int c = ldeg[t];
            c = c < ROW_STRIDE ? c : ROW_STRIDE;
            const int cp = (c + 7) & ~7;
            for (int j = c; j < cp; ++j) rows[(size_t)n * ROW_STRIDE + j] = SENT;
            deg[n] = cp;
        }
    }
}

// ---------------------------------------------------------------------------
// Node-centric GATv2: one wave per dst node, 8 lanes/edge (8 bf16 ch/lane),
// 8 edges per wave-instruction. score = 0.6*(al_s + ar_d) + 0.4*sum att|u|.
// L1: al stride-2 per head; output packed bf16 (feeds gemm2's MFMA A).
// L2: al pre-summed; output f32 (feeds pool).
// ---------------------------------------------------------------------------
template <bool L1>
__global__ __launch_bounds__(256) void node_layer(
    const int* __restrict__ deg, const int* __restrict__ rows,
    const u32* __restrict__ xlb, const float* __restrict__ xr,
    const float* __restrict__ alb, const float* __restrict__ arb,
    const float* __restrict__ att, const float* __restrict__ bias,
    u32* __restrict__ houtB, float* __restrict__ houtF) {
    const int n = (blockIdx.x * 256 + threadIdx.x) >> 6;
    const int lane = threadIdx.x & 63;
    const int sub = lane & 7;        // channel octet: ch = sub*8 .. +7
    const int g = lane >> 3;         // edge slot 0..7
    const float4 xra = *(const float4*)(xr + (size_t)n * 64 + sub * 8);
    const float4 xrb = *(const float4*)(xr + (size_t)n * 64 + sub * 8 + 4);
    const float4 ata = *(const float4*)(att + sub * 8);
    const float4 atb = *(const float4*)(att + sub * 8 + 4);
    const float2 ar2 = *(const float2*)(arb + (size_t)n * 2);
    const float based = 0.6f * (L1 ? ((sub & 4) ? ar2.y : ar2.x) : (ar2.x + ar2.y));

    float c0 = 0.f, c1 = 0.f, c2 = 0.f, c3 = 0.f;
    float c4 = 0.f, c5 = 0.f, c6 = 0.f, c7 = 0.f;
    float ssum = 0.f;
    const int cp = __builtin_amdgcn_readfirstlane(deg[n]);
    const int* __restrict__ row = rows + (size_t)n * ROW_STRIDE;
    for (int i = 0; i < cp; i += 8) {
        const int s = row[i + g];
        const float als = L1 ? alb[(size_t)s * 2 + ((sub >> 2) & 1)] : alb[s];
        const uint4 r4 = *(const uint4*)(xlb + (size_t)s * 32 + sub * 4);
        const float a0 = bcf(r4.x << 16), a1 = bcf(r4.x & 0xFFFF0000u);
        const float a2f = bcf(r4.y << 16), a3 = bcf(r4.y & 0xFFFF0000u);
        const float a4 = bcf(r4.z << 16), a5 = bcf(r4.z & 0xFFFF0000u);
        const float a6 = bcf(r4.w << 16), a7 = bcf(r4.w & 0xFFFF0000u);
        float v = ata.x * fabsf(a0 + xra.x);
        v = fmaf(ata.y, fabsf(a1 + xra.y), v);
        v = fmaf(ata.z, fabsf(a2f + xra.z), v);
        v = fmaf(ata.w, fabsf(a3 + xra.w), v);
        v = fmaf(atb.x, fabsf(a4 + xrb.x), v);
        v = fmaf(atb.y, fabsf(a5 + xrb.y), v);
        v = fmaf(atb.z, fabsf(a6 + xrb.z), v);
        v = fmaf(atb.w, fabsf(a7 + xrb.w), v);
        v = dpp_add<0xB1>(v);            // xor 1
        v = dpp_add<0x4E>(v);            // xor 2  (L1: 4-lane head reduce done)
        if (!L1) v = dpp_add<0x141>(v);  // row_half_mirror: 8-lane reduce
        const float ev = __expf(fmaf(0.6f, als, fmaf(0.4f, v, based)));
        c0 = fmaf(ev, a0, c0); c1 = fmaf(ev, a1, c1);
        c2 = fmaf(ev, a2f, c2); c3 = fmaf(ev, a3, c3);
        c4 = fmaf(ev, a4, c4); c5 = fmaf(ev, a5, c5);
        c6 = fmaf(ev, a6, c6); c7 = fmaf(ev, a7, c7);
        ssum += ev;
    }
#define XRED(x) x += __shfl_xor(x, 8); x += __shfl_xor(x, 16); x += __shfl_xor(x, 32);
    XRED(c0) XRED(c1) XRED(c2) XRED(c3) XRED(c4) XRED(c5) XRED(c6) XRED(c7) XRED(ssum)
#undef XRED
    if (g == 0) {
        const float inv = 1.f / (ssum + 1e-16f);
        const float4 ba = *(const float4*)(bias + sub * 8);
        const float4 bb = *(const float4*)(bias + sub * 8 + 4);
        float o[8] = {c0 * inv + ba.x, c1 * inv + ba.y, c2 * inv + ba.z, c3 * inv + ba.w,
                      c4 * inv + bb.x, c5 * inv + bb.y, c6 * inv + bb.z, c7 * inv + bb.w};
#pragma unroll
        for (int j = 0; j < 8; ++j) o[j] = o[j] > 0.f ? o[j] : expm1f(o[j]);
        if (L1) {
            *(uint4*)(houtB + (size_t)n * 32 + sub * 4) = make_uint4(
                pack_bf16x2(o[0], o[1]), pack_bf16x2(o[2], o[3]),
                pack_bf16x2(o[4], o[5]), pack_bf16x2(o[6], o[7]));
        } else {
            *(float4*)(houtF + (size_t)n * 64 + sub * 8) = make_float4(o[0], o[1], o[2], o[3]);
            *(float4*)(houtF + (size_t)n * 64 + sub * 8 + 4) = make_float4(o[4], o[5], o[6], o[7]);
        }
    }
}

// ---------------------------------------------------------------------------
// Mean-pool + fused head. 256-thread blocks; wave w owns the contiguous
// 8-node run [blk*32 + w*8, +8) -> serial depth 8, ~6252 waves of TLP
// (R14's 64-deep/782-wave version was latency-bound at 60 us). Sorted batch
// -> ~1 segment flush per wave. LAST block computes pooled@lin_w + lin_b.
// ---------------------------------------------------------------------------
__global__ __launch_bounds__(256) void pool_head(
    const float* __restrict__ h2, const int* __restrict__ batch,
    float* __restrict__ pooled, float* __restrict__ cnt,
    const float* __restrict__ lin_w, const float* __restrict__ lin_b,
    float* __restrict__ out, int* __restrict__ done2, int nblocks) {
    __shared__ int lastFlag;
    const int t = threadIdx.x;
    const int lane = t & 63;
    const int w = t >> 6;
    const int base = blockIdx.x * PB_NODES + w * 8;
    float local = 0.f, lc = 0.f;
    int cur = -1;
#pragma unroll
    for (int j = 0; j < 8; ++j) {
        const int n = base + j;
        if (n >= N_NODES) break;
        const int g = batch[n];
        if (g != cur) {
            if (cur >= 0) {
                unsafeAtomicAdd(&pooled[cur * 64 + lane], local);
                if (lane == 0) unsafeAtomicAdd(&cnt[cur], lc);
            }
            cur = g; local = 0.f; lc = 0.f;
        }
        local += h2[(size_t)n * 64 + lane];
        lc += 1.f;
    }
    if (cur >= 0) {
        unsafeAtomicAdd(&pooled[cur * 64 + lane], local);
        if (lane == 0) unsafeAtomicAdd(&cnt[cur], lc);
    }
    __threadfence();
    if (t == 0) lastFlag = (atomicAdd(done2, 1) == nblocks - 1);
    __syncthreads();
    if (!lastFlag) return;
    __threadfence();   // acquire: see all pooled/cnt atomics
    if (t < 128) {
        const int g = t >> 1, k = t & 1;   // (graph, output col)
        float c = cnt[g];
        c = c > 1.f ? c : 1.f;
        float a = 0.f;
#pragma unroll
        for (int j = 0; j < 64; ++j) a = fmaf(pooled[g * 64 + j] / c, lin_w[j * 2 + k], a);
        out[t] = a + lin_b[k];
    }
}

extern "C" void kernel_launch(void* const* d_in, const int* in_sizes, int n_in,
                              void* d_out, int out_size, void* d_ws, size_t ws_size,
                              hipStream_t stream) {
    const float* x     = (const float*)d_in[0];
    const int*   ei    = (const int*)d_in[1];
    const int*   batch = (const int*)d_in[2];
    const float* Wl1   = (const float*)d_in[3];
    const float* Wr1   = (const float*)d_in[4];
    const float* att1  = (const float*)d_in[5];
    const float* b1    = (const float*)d_in[6];
    const float* Wl2   = (const float*)d_in[7];
    const float* Wr2   = (const float*)d_in[8];
    const float* att2  = (const float*)d_in[9];
    const float* b2    = (const float*)d_in[10];
    const float* lin_w = (const float*)d_in[11];
    const float* lin_b = (const float*)d_in[12];

    float* ws = (float*)d_ws;     // offsets in dwords
    u32*   h1b      = (u32*)ws;                    //  1,601,536 (50048*32)
    u32*   xlb      = (u32*)(ws + 1601536);        //  1,601,536
    float* xr       = ws + 3203072;                //  3,203,072 (50048*64)
    float* h2       = ws + 6406144;                //  3,203,072
    float* alb      = ws + 9609216;                //    100,096
    float* arb      = ws + 9709312;                //    100,096
    int*   rows     = (int*)(ws + 9809408);        //  4,003,840 (50048*80)
    int*   deg      = (int*)(ws + 13813248);       //     50,048
    int*   countsRM = (int*)(ws + 13863296);       //    100,096 (256*391)
    int*   scanT    = (int*)(ws + 13963392);       //    100,096
    int*   totals   = (int*)(ws + 14063488);       //        512
    int*   bb       = (int*)(ws + 14064000);       //        512
    int*   sortedE  = (int*)(ws + 14064512);       //  1,600,000
    u32*   wf1hi    = (u32*)(ws + 15664512);       //      8,192
    u32*   wf1lo    = (u32*)(ws + 15672704);       //      8,192
    u32*   wf2hi    = (u32*)(ws + 15680896);       //      4,096
    u32*   wf2lo    = (u32*)(ws + 15684992);       //      4,096
    float* pooled   = ws + 15689088;               //      4,096  -- memset start
    float* cnt      = ws + 15693184;               //         64
    int*   done2    = (int*)(ws + 15693248);       //          1
    // total ~15.7M dwords ~= 63 MB (ws is 256 MiB)

    // zero pooled + cnt + done counter (one contiguous region)
    hipMemsetAsync(pooled, 0, (size_t)(4096 + 64 + 1) * sizeof(float), stream);

    const int gblocks = (N_NODES + 63) / 64;   // 782

    // ---- build prologue: histogram (+W-frag riders) + parallel scans ----
    count_kernel<<<NBLK + 2, 256, 0, stream>>>(
        ei, countsRM, Wl1, Wr1, Wl2, Wr2, wf1hi, wf1lo, wf2hi, wf2lo);
    scan_bucket<<<NB, 256, 0, stream>>>(countsRM, scanT, totals);
    scan_total<<<1, 512, 0, stream>>>(totals, bb, alb);

    // ---- layer-1 MFMA gemm (direct f32 x) fused with radix scatter ----
    gemm_mfma<128, true, true><<<gblocks + NBLK, 256, 0, stream>>>(
        x, nullptr, wf1hi, wf1lo, att1, xlb, xr, alb, arb,
        ei, scanT, bb, sortedE, gblocks);

    expand_kernel<<<NB, 256, 0, stream>>>(bb, sortedE, deg, rows);

    // ---- layer 1 node pass (emits packed bf16 h1) ----
    node_layer<true><<<N_NODES / 4, 256, 0, stream>>>(
        deg, rows, xlb, xr, alb, arb, att1, b1, h1b, nullptr);

    // ---- layer 2 ----
    gemm_mfma<64, false, false><<<gblocks, 256, 0, stream>>>(
        nullptr, h1b, wf2hi, wf2lo, att2, xlb, xr, alb, arb,
        nullptr, nullptr, nullptr, nullptr, gblocks);
    node_layer<false><<<N_NODES / 4, 256, 0, stream>>>(
        deg, rows, xlb, xr, alb, arb, att2, b2, nullptr, h2);

    // ---- pool + fused head (parallel, last-block head) ----
    const int pblocks = (N_NODES + PB_NODES - 1) / PB_NODES;   // 1563
    pool_head<<<pblocks, 256, 0, stream>>>(
        h2, batch, pooled, cnt, lin_w, lin_b, (float*)d_out, done2, pblocks);
}

// Round 16
// 269.627 us; speedup vs baseline: 1.3825x; 1.3825x over previous
//
#include <hip/hip_runtime.h>
#include <hip/hip_bf16.h>
#include <math.h>

#define N_NODES 50000
#define N_EDGES 1600000
#define N_GRAPHS 64
#define NB 391             // dst buckets of 128 nodes: b = dst >> 7
#define NBLK 256           // partition blocks
#define CHUNK 6250         // edges per partition block (256*6250 = 1.6M exactly)
#define ROW_STRIDE 80      // per-node adjacency capacity (multiple of 8)
#define SENT 50047         // sentinel node: al[SENT] = -1e30 -> exp(score) = 0

typedef unsigned int u32;
typedef __attribute__((ext_vector_type(8))) __bf16 bf16x8;
typedef __attribute__((ext_vector_type(4))) float f32x4;

__device__ __forceinline__ float bcf(u32 u) { return __builtin_bit_cast(float, u); }

template <int CTRL>
__device__ __forceinline__ float dpp_add(float v) {
    int r = __builtin_amdgcn_update_dpp(0, __builtin_bit_cast(int, v), CTRL, 0xF, 0xF, true);
    return v + __builtin_bit_cast(float, r);
}

__device__ __forceinline__ u32 pack_bf16x2(float lo, float hi) {
    unsigned short l = __builtin_bit_cast(unsigned short, __float2bfloat16(lo));
    unsigned short h = __builtin_bit_cast(unsigned short, __float2bfloat16(hi));
    return (u32)l | ((u32)h << 16);
}

// ---------------------------------------------------------------------------
// W -> MFMA-B-fragment layout, hi/lo residual split (device helper; rides the
// count grid as blocks 256/257).
// ---------------------------------------------------------------------------
__device__ __forceinline__ void conv_w_dev(
    int K, const float* __restrict__ Wl, const float* __restrict__ Wr,
    u32* __restrict__ wfHi, u32* __restrict__ wfLo) {
    const int KO = K / 32;
    for (int idx = threadIdx.x; idx < KO * 8 * 64; idx += 256) {
        const int L = idx & 63;
        const int tile = idx >> 6;
        const int ko = tile >> 3, nt = tile & 7;
        const int c = nt * 16 + (L & 15);
        u32 hi[4], lo[4];
        float hv[8], lv[8];
#pragma unroll
        for (int i = 0; i < 8; ++i) {
            const int k = ko * 32 + (L >> 4) * 8 + i;
            const float wv = (c < 64) ? Wl[k * 64 + c] : Wr[k * 64 + (c - 64)];
            const __hip_bfloat16 h = __float2bfloat16(wv);
            hv[i] = wv;
            lv[i] = wv - __bfloat162float(h);
        }
#pragma unroll
        for (int i = 0; i < 4; ++i) {
            hi[i] = pack_bf16x2(hv[2 * i], hv[2 * i + 1]);
            lo[i] = pack_bf16x2(lv[2 * i], lv[2 * i + 1]);
        }
        *(uint4*)(wfHi + (size_t)idx * 4) = make_uint4(hi[0], hi[1], hi[2], hi[3]);
        *(uint4*)(wfLo + (size_t)idx * 4) = make_uint4(lo[0], lo[1], lo[2], lo[3]);
    }
}

// Blocks 0..255: per-chunk dst-bucket histogram -> countsRM[blk][bucket].
// Block 256/257: W-fragment conversion. Block 258: binary-search the sorted
// batch for the 64 graph start indices -> gstart[65] (independent riders).
__global__ __launch_bounds__(256) void count_kernel(
    const int* __restrict__ ei, int* __restrict__ countsRM,
    const float* __restrict__ Wl1, const float* __restrict__ Wr1,
    const float* __restrict__ Wl2, const float* __restrict__ Wr2,
    u32* __restrict__ wf1hi, u32* __restrict__ wf1lo,
    u32* __restrict__ wf2hi, u32* __restrict__ wf2lo,
    const int* __restrict__ batch, int* __restrict__ gstart) {
    if (blockIdx.x == 256) { conv_w_dev(128, Wl1, Wr1, wf1hi, wf1lo); return; }
    if (blockIdx.x == 257) { conv_w_dev(64, Wl2, Wr2, wf2hi, wf2lo); return; }
    if (blockIdx.x == 258) {
        const int g = threadIdx.x;
        if (g < N_GRAPHS) {
            int lo = 0, hi = N_NODES;
            while (lo < hi) {               // lower_bound(batch, g)
                const int mid = (lo + hi) >> 1;
                if (batch[mid] < g) lo = mid + 1; else hi = mid;
            }
            gstart[g] = lo;
        }
        if (threadIdx.x == 0) gstart[N_GRAPHS] = N_NODES;
        return;
    }
    __shared__ int h[NB];
    const int t = threadIdx.x;
    for (int k = t; k < NB; k += 256) h[k] = 0;
    __syncthreads();
    const int base = blockIdx.x * CHUNK;
    for (int e = base + t; e < base + CHUNK; e += 256)
        atomicAdd(&h[ei[N_EDGES + e] >> 7], 1);
    __syncthreads();
    for (int k = t; k < NB; k += 256) countsRM[blockIdx.x * NB + k] = h[k];
}

// One block per bucket: parallel exclusive scan over the 256 block counts.
__global__ __launch_bounds__(256) void scan_bucket(
    const int* __restrict__ countsRM, int* __restrict__ scanT,
    int* __restrict__ totals) {
    __shared__ int tmp[256];
    const int b = blockIdx.x;
    const int t = threadIdx.x;
    const int v0 = countsRM[t * NB + b];
    tmp[t] = v0;
    __syncthreads();
    for (int off = 1; off < 256; off <<= 1) {
        int v = (t >= off) ? tmp[t - off] : 0;
        __syncthreads();
        tmp[t] += v;
        __syncthreads();
    }
    scanT[b * 256 + t] = tmp[t] - v0;   // exclusive
    if (t == 255) totals[b] = tmp[t];
}

__global__ __launch_bounds__(512) void scan_total(
    const int* __restrict__ totals, int* __restrict__ bucketBase,
    float* __restrict__ alb) {
    __shared__ int tmp[512];
    const int t = threadIdx.x;
    const int v0 = (t < NB) ? totals[t] : 0;
    tmp[t] = v0;
    __syncthreads();
    for (int off = 1; off < 512; off <<= 1) {
        int v = (t >= off) ? tmp[t - off] : 0;
        __syncthreads();
        tmp[t] += v;
        __syncthreads();
    }
    if (t < NB) bucketBase[t] = tmp[t] - v0;
    if (t == NB - 1) bucketBase[NB] = tmp[t];
    // L1-layout sentinel (indices 100094/100095; gemm writes only < 100000)
    if (t == 0) { alb[(size_t)SENT * 2] = -1e30f; alb[(size_t)SENT * 2 + 1] = -1e30f; }
}

// ---------------------------------------------------------------------------
// MFMA dense transform: [xl|xr] = x @ [Wl|Wr] via bf16 16x16x32 MFMA, W hi/lo
// residual (f32 acc -> W-rounding negligible). AF32: A is f32, packed to bf16
// in-register (layer 1); else A is packed-bf16 rows (h1 for layer 2).
// Epilogue through padded LDS tile: xl->bf16 pack, xr->f32, att-dots al/ar.
// FUSE_SCATTER: blocks >= gemmBlocks run the radix scatter (LDS aliased).
// K==64: al pre-summed; block 0 sets L2 sentinel.
// ---------------------------------------------------------------------------
template <int K, bool AF32, bool FUSE_SCATTER>
__global__ __launch_bounds__(256) void gemm_mfma(
    const float* __restrict__ xF, const u32* __restrict__ xB,
    const u32* __restrict__ wfHi, const u32* __restrict__ wfLo,
    const float* __restrict__ att,
    u32* __restrict__ xlb, float* __restrict__ xr,
    float* __restrict__ alb, float* __restrict__ arb,
    const int* __restrict__ ei, const int* __restrict__ scanT,
    const int* __restrict__ bb, int* __restrict__ sortedE, int gemmBlocks) {
    __shared__ float Ct[64][129];   // +1 pad: column reads conflict-free
    __shared__ float alq[64][4];
    const int t = threadIdx.x;
    if (FUSE_SCATTER && blockIdx.x >= gemmBlocks) {
        int* cursor = (int*)&Ct[0][0];
        const int b = blockIdx.x - gemmBlocks;
        for (int k = t; k < NB; k += 256)
            cursor[k] = bb[k] + scanT[k * 256 + b];
        __syncthreads();
        const int base = b * CHUNK;
        for (int e = base + t; e < base + CHUNK; e += 256) {
            const int s = ei[e];
            const int d = ei[N_EDGES + e];
            const int idx = atomicAdd(&cursor[d >> 7], 1);   // LDS atomic
            sortedE[idx] = (s << 7) | (d & 127);
        }
        return;
    }
    const int KO = K / 32;
    const int lane = t & 63;
    const int w = __builtin_amdgcn_readfirstlane(t >> 6);
    const int quad = lane >> 4;
    const int m16 = lane & 15;
    const int base = blockIdx.x * 64;
    const int arow = base + w * 16 + m16;
    const int rowc = arow < N_NODES ? arow : N_NODES - 1;   // clamp (safe loads)

    f32x4 acc[8];
    const f32x4 zz = {0.f, 0.f, 0.f, 0.f};
#pragma unroll
    for (int i = 0; i < 8; ++i) acc[i] = zz;

#pragma unroll
    for (int ko = 0; ko < KO; ++ko) {
        bf16x8 af;
        if (AF32) {
            const float* ap = xF + (size_t)rowc * K + ko * 32 + quad * 8;
            const float4 a0 = *(const float4*)ap;
            const float4 a1 = *(const float4*)(ap + 4);
            af = __builtin_bit_cast(bf16x8, make_uint4(
                pack_bf16x2(a0.x, a0.y), pack_bf16x2(a0.z, a0.w),
                pack_bf16x2(a1.x, a1.y), pack_bf16x2(a1.z, a1.w)));
        } else {
            af = __builtin_bit_cast(bf16x8,
                *(const uint4*)(xB + ((size_t)rowc * K + ko * 32 + quad * 8) / 2));
        }
#pragma unroll
        for (int nt = 0; nt < 8; ++nt) {
            const uint4 bh = *(const uint4*)(wfHi + (size_t)((ko * 8 + nt) * 64 + lane) * 4);
            acc[nt] = __builtin_amdgcn_mfma_f32_16x16x32_bf16(
                af, __builtin_bit_cast(bf16x8, bh), acc[nt], 0, 0, 0);
        }
#pragma unroll
        for (int nt = 0; nt < 8; ++nt) {
            const uint4 bl = *(const uint4*)(wfLo + (size_t)((ko * 8 + nt) * 64 + lane) * 4);
            acc[nt] = __builtin_amdgcn_mfma_f32_16x16x32_bf16(
                af, __builtin_bit_cast(bf16x8, bl), acc[nt], 0, 0, 0);
        }
    }
    // C/D layout: col = lane&15, row = quad*4 + reg   [verified mapping]
#pragma unroll
    for (int nt = 0; nt < 8; ++nt)
#pragma unroll
        for (int r = 0; r < 4; ++r)
            Ct[w * 16 + quad * 4 + r][nt * 16 + m16] = acc[nt][r];
    __syncthreads();

    const int node = t & 63;
    const int q = t >> 6;          // quarter: 0,1 -> xl cols; 2,3 -> xr cols
    const int n = base + node;
    float av = 0.f;
    if (n < N_NODES) {
        if (q < 2) {
            u32 pk[16];
#pragma unroll
            for (int j = 0; j < 32; j += 2) {
                const float v0 = Ct[node][q * 32 + j];
                const float v1 = Ct[node][q * 32 + j + 1];
                av = fmaf(att[q * 32 + j], v0, av);
                av = fmaf(att[q * 32 + j + 1], v1, av);
                pk[j >> 1] = pack_bf16x2(v0, v1);
            }
            uint4* dst = (uint4*)(xlb + (size_t)n * 32 + q * 16);
#pragma unroll
            for (int j = 0; j < 4; ++j)
                dst[j] = make_uint4(pk[j * 4], pk[j * 4 + 1], pk[j * 4 + 2], pk[j * 4 + 3]);
        } else {
            const int cb = (q - 2) * 32;
#pragma unroll
            for (int j = 0; j < 32; j += 4) {
                float4 v = {Ct[node][64 + cb + j], Ct[node][64 + cb + j + 1],
                            Ct[node][64 + cb + j + 2], Ct[node][64 + cb + j + 3]};
                av = fmaf(att[cb + j], v.x, av);
                av = fmaf(att[cb + j + 1], v.y, av);
                av = fmaf(att[cb + j + 2], v.z, av);
                av = fmaf(att[cb + j + 3], v.w, av);
                *(float4*)(xr + (size_t)n * 64 + cb + j) = v;
            }
        }
    }
    alq[node][q] = av;
    __syncthreads();
    if (t < 64 && base + t < N_NODES) {
        const int nn = base + t;
        if (K == 128) {
            alb[(size_t)nn * 2] = alq[t][0];
            alb[(size_t)nn * 2 + 1] = alq[t][1];
        } else {
            alb[nn] = alq[t][0] + alq[t][1];   // pre-summed for L2
        }
        arb[(size_t)nn * 2] = alq[t][2];
        arb[(size_t)nn * 2 + 1] = alq[t][3];
    }
    if (K == 64 && blockIdx.x == 0 && t == 0) alb[SENT] = -1e30f;   // L2 sentinel
}

// Expand: self-loop pre-seeded as entry 0; rows padded to x8 with SENT.
__global__ __launch_bounds__(256) void expand_kernel(
    const int* __restrict__ bucketBase, const int* __restrict__ sortedE,
    int* __restrict__ deg, int* __restrict__ rows) {
    __shared__ int ldeg[128];
    const int b = blockIdx.x;
    const int t = threadIdx.x;
    const int node_base = b * 128;
    if (t < 128) {
        const int n = node_base + t;
        ldeg[t] = 1;
        if (n < N_NODES) rows[(size_t)n * ROW_STRIDE] = n;   // self loop
    }
    __syncthreads();
    const int beg = bucketBase[b];
    const int end = bucketBase[b + 1];
    for (int i = beg + t; i < end; i += 256) {
        const int en = sortedE[i];
        const int ld = en & 127;
        const int pos = atomicAdd(&ldeg[ld], 1);
        if (pos < ROW_STRIDE) rows[(size_t)(node_base + ld) * ROW_STRIDE + pos] = en >> 7;
    }
    __syncthreads();
    if (t < 128) {
        const int n = node_base + t;
        if (n < N_NODES) {
            int c = ldeg[t];
            c = c < ROW_STRIDE ? c : ROW_STRIDE;
            const int cp = (c + 7) & ~7;
            for (int j = c; j < cp; ++j) rows[(size_t)n * ROW_STRIDE + j] = SENT;
            deg[n] = cp;
        }
    }
}

// ---------------------------------------------------------------------------
// Node-centric GATv2: one wave per dst node, 8 lanes/edge (8 bf16 ch/lane),
// 8 edges per wave-instruction. score = 0.6*(al_s + ar_d) + 0.4*sum att|u|.
// L1: al stride-2 per head; output packed bf16 (feeds gemm2's MFMA A).
// L2: al pre-summed; output f32 (feeds pool).
// ---------------------------------------------------------------------------
template <bool L1>
__global__ __launch_bounds__(256) void node_layer(
    const int* __restrict__ deg, const int* __restrict__ rows,
    const u32* __restrict__ xlb, const float* __restrict__ xr,
    const float* __restrict__ alb, const float* __restrict__ arb,
    const float* __restrict__ att, const float* __restrict__ bias,
    u32* __restrict__ houtB, float* __restrict__ houtF) {
    const int n = (blockIdx.x * 256 + threadIdx.x) >> 6;
    const int lane = threadIdx.x & 63;
    const int sub = lane & 7;        // channel octet: ch = sub*8 .. +7
    const int g = lane >> 3;         // edge slot 0..7
    const float4 xra = *(const float4*)(xr + (size_t)n * 64 + sub * 8);
    const float4 xrb = *(const float4*)(xr + (size_t)n * 64 + sub * 8 + 4);
    const float4 ata = *(const float4*)(att + sub * 8);
    const float4 atb = *(const float4*)(att + sub * 8 + 4);
    const float2 ar2 = *(const float2*)(arb + (size_t)n * 2);
    const float based = 0.6f * (L1 ? ((sub & 4) ? ar2.y : ar2.x) : (ar2.x + ar2.y));

    float c0 = 0.f, c1 = 0.f, c2 = 0.f, c3 = 0.f;
    float c4 = 0.f, c5 = 0.f, c6 = 0.f, c7 = 0.f;
    float ssum = 0.f;
    const int cp = __builtin_amdgcn_readfirstlane(deg[n]);
    const int* __restrict__ row = rows + (size_t)n * ROW_STRIDE;
    for (int i = 0; i < cp; i += 8) {
        const int s = row[i + g];
        const float als = L1 ? alb[(size_t)s * 2 + ((sub >> 2) & 1)] : alb[s];
        const uint4 r4 = *(const uint4*)(xlb + (size_t)s * 32 + sub * 4);
        const float a0 = bcf(r4.x << 16), a1 = bcf(r4.x & 0xFFFF0000u);
        const float a2f = bcf(r4.y << 16), a3 = bcf(r4.y & 0xFFFF0000u);
        const float a4 = bcf(r4.z << 16), a5 = bcf(r4.z & 0xFFFF0000u);
        const float a6 = bcf(r4.w << 16), a7 = bcf(r4.w & 0xFFFF0000u);
        float v = ata.x * fabsf(a0 + xra.x);
        v = fmaf(ata.y, fabsf(a1 + xra.y), v);
        v = fmaf(ata.z, fabsf(a2f + xra.z), v);
        v = fmaf(ata.w, fabsf(a3 + xra.w), v);
        v = fmaf(atb.x, fabsf(a4 + xrb.x), v);
        v = fmaf(atb.y, fabsf(a5 + xrb.y), v);
        v = fmaf(atb.z, fabsf(a6 + xrb.z), v);
        v = fmaf(atb.w, fabsf(a7 + xrb.w), v);
        v = dpp_add<0xB1>(v);            // xor 1
        v = dpp_add<0x4E>(v);            // xor 2  (L1: 4-lane head reduce done)
        if (!L1) v = dpp_add<0x141>(v);  // row_half_mirror: 8-lane reduce
        const float ev = __expf(fmaf(0.6f, als, fmaf(0.4f, v, based)));
        c0 = fmaf(ev, a0, c0); c1 = fmaf(ev, a1, c1);
        c2 = fmaf(ev, a2f, c2); c3 = fmaf(ev, a3, c3);
        c4 = fmaf(ev, a4, c4); c5 = fmaf(ev, a5, c5);
        c6 = fmaf(ev, a6, c6); c7 = fmaf(ev, a7, c7);
        ssum += ev;
    }
#define XRED(x) x += __shfl_xor(x, 8); x += __shfl_xor(x, 16); x += __shfl_xor(x, 32);
    XRED(c0) XRED(c1) XRED(c2) XRED(c3) XRED(c4) XRED(c5) XRED(c6) XRED(c7) XRED(ssum)
#undef XRED
    if (g == 0) {
        const float inv = 1.f / (ssum + 1e-16f);
        const float4 ba = *(const float4*)(bias + sub * 8);
        const float4 bb = *(const float4*)(bias + sub * 8 + 4);
        float o[8] = {c0 * inv + ba.x, c1 * inv + ba.y, c2 * inv + ba.z, c3 * inv + ba.w,
                      c4 * inv + bb.x, c5 * inv + bb.y, c6 * inv + bb.z, c7 * inv + bb.w};
#pragma unroll
        for (int j = 0; j < 8; ++j) o[j] = o[j] > 0.f ? o[j] : expm1f(o[j]);
        if (L1) {
            *(uint4*)(houtB + (size_t)n * 32 + sub * 4) = make_uint4(
                pack_bf16x2(o[0], o[1]), pack_bf16x2(o[2], o[3]),
                pack_bf16x2(o[4], o[5]), pack_bf16x2(o[6], o[7]));
        } else {
            *(float4*)(houtF + (size_t)n * 64 + sub * 8) = make_float4(o[0], o[1], o[2], o[3]);
            *(float4*)(houtF + (size_t)n * 64 + sub * 8 + 4) = make_float4(o[4], o[5], o[6], o[7]);
        }
    }
}

// ---------------------------------------------------------------------------
// Atomic-free pooling, phase A: block = (graph g, strip s of 8). Exact node
// range from gstart; 4 waves stride nodes (lane = channel, coalesced 256B
// loads, 2 ILP chains); LDS-reduce across waves; dense partial write.
// ---------------------------------------------------------------------------
__global__ __launch_bounds__(256) void pool_partial(
    const float* __restrict__ h2, const int* __restrict__ gstart,
    float* __restrict__ partial) {
    __shared__ float ps[4][64];
    const int gs = blockIdx.x;
    const int g = gs >> 3, s = gs & 7;
    const int t = threadIdx.x;
    const int lane = t & 63;
    const int w = t >> 6;
    const int beg = gstart[g], end = gstart[g + 1];
    const int len = end - beg;
    const int chunk = (len + 7) >> 3;
    const int lo = beg + s * chunk;
    const int hi = min(lo + chunk, end);
    float a0 = 0.f, a1 = 0.f;
    int n = lo + w;
    for (; n + 4 < hi; n += 8) {
        a0 += h2[(size_t)n * 64 + lane];
        a1 += h2[(size_t)(n + 4) * 64 + lane];
    }
    if (n < hi) a0 += h2[(size_t)n * 64 + lane];
    ps[w][lane] = a0 + a1;
    __syncthreads();
    if (t < 64)
        partial[(size_t)gs * 64 + t] = ps[0][t] + ps[1][t] + ps[2][t] + ps[3][t];
}

// Phase B + head: one wave per graph; sum the 8 strip partials, divide by
// max(cnt,1), 64-lane butterfly dot with lin_w. No atomics, no fences.
__global__ __launch_bounds__(64) void pool_head2(
    const float* __restrict__ partial, const int* __restrict__ gstart,
    const float* __restrict__ lin_w, const float* __restrict__ lin_b,
    float* __restrict__ out) {
    const int g = blockIdx.x;
    const int t = threadIdx.x;
    float sum = 0.f;
#pragma unroll
    for (int s = 0; s < 8; ++s) sum += partial[(size_t)(g * 8 + s) * 64 + t];
    float c = (float)(gstart[g + 1] - gstart[g]);
    c = c > 1.f ? c : 1.f;
    const float m = sum / c;
    float v0 = m * lin_w[t * 2];
    float v1 = m * lin_w[t * 2 + 1];
#pragma unroll
    for (int off = 1; off < 64; off <<= 1) {
        v0 += __shfl_xor(v0, off);
        v1 += __shfl_xor(v1, off);
    }
    if (t == 0) {
        out[g * 2] = v0 + lin_b[0];
        out[g * 2 + 1] = v1 + lin_b[1];
    }
}

extern "C" void kernel_launch(void* const* d_in, const int* in_sizes, int n_in,
                              void* d_out, int out_size, void* d_ws, size_t ws_size,
                              hipStream_t stream) {
    const float* x     = (const float*)d_in[0];
    const int*   ei    = (const int*)d_in[1];
    const int*   batch = (const int*)d_in[2];
    const float* Wl1   = (const float*)d_in[3];
    const float* Wr1   = (const float*)d_in[4];
    const float* att1  = (const float*)d_in[5];
    const float* b1    = (const float*)d_in[6];
    const float* Wl2   = (const float*)d_in[7];
    const float* Wr2   = (const float*)d_in[8];
    const float* att2  = (const float*)d_in[9];
    const float* b2    = (const float*)d_in[10];
    const float* lin_w = (const float*)d_in[11];
    const float* lin_b = (const float*)d_in[12];

    float* ws = (float*)d_ws;     // offsets in dwords
    u32*   h1b      = (u32*)ws;                    //  1,601,536 (50048*32)
    u32*   xlb      = (u32*)(ws + 1601536);        //  1,601,536
    float* xr       = ws + 3203072;                //  3,203,072 (50048*64)
    float* h2       = ws + 6406144;                //  3,203,072
    float* alb      = ws + 9609216;                //    100,096
    float* arb      = ws + 9709312;                //    100,096
    int*   rows     = (int*)(ws + 9809408);        //  4,003,840 (50048*80)
    int*   deg      = (int*)(ws + 13813248);       //     50,048
    int*   countsRM = (int*)(ws + 13863296);       //    100,096 (256*391)
    int*   scanT    = (int*)(ws + 13963392);       //    100,096
    int*   totals   = (int*)(ws + 14063488);       //        512
    int*   bb       = (int*)(ws + 14064000);       //        512
    int*   sortedE  = (int*)(ws + 14064512);       //  1,600,000
    u32*   wf1hi    = (u32*)(ws + 15664512);       //      8,192
    u32*   wf1lo    = (u32*)(ws + 15672704);       //      8,192
    u32*   wf2hi    = (u32*)(ws + 15680896);       //      4,096
    u32*   wf2lo    = (u32*)(ws + 15684992);       //      4,096
    int*   gstart   = (int*)(ws + 15689088);       //        128
    float* partial  = ws + 15689216;               //     32,768 (512*64)
    // total ~15.72M dwords ~= 63 MB (ws is 256 MiB)
    // NOTE: no global atomics anywhere -> no memset needed.

    const int gblocks = (N_NODES + 63) / 64;   // 782

    // ---- build prologue: histogram + riders (W-frags, graph starts) ----
    count_kernel<<<NBLK + 3, 256, 0, stream>>>(
        ei, countsRM, Wl1, Wr1, Wl2, Wr2, wf1hi, wf1lo, wf2hi, wf2lo,
        batch, gstart);
    scan_bucket<<<NB, 256, 0, stream>>>(countsRM, scanT, totals);
    scan_total<<<1, 512, 0, stream>>>(totals, bb, alb);

    // ---- layer-1 MFMA gemm (direct f32 x) fused with radix scatter ----
    gemm_mfma<128, true, true><<<gblocks + NBLK, 256, 0, stream>>>(
        x, nullptr, wf1hi, wf1lo, att1, xlb, xr, alb, arb,
        ei, scanT, bb, sortedE, gblocks);

    expand_kernel<<<NB, 256, 0, stream>>>(bb, sortedE, deg, rows);

    // ---- layer 1 node pass (emits packed bf16 h1) ----
    node_layer<true><<<N_NODES / 4, 256, 0, stream>>>(
        deg, rows, xlb, xr, alb, arb, att1, b1, h1b, nullptr);

    // ---- layer 2 ----
    gemm_mfma<64, false, false><<<gblocks, 256, 0, stream>>>(
        nullptr, h1b, wf2hi, wf2lo, att2, xlb, xr, alb, arb,
        nullptr, nullptr, nullptr, nullptr, gblocks);
    node_layer<false><<<N_NODES / 4, 256, 0, stream>>>(
        deg, rows, xlb, xr, alb, arb, att2, b2, nullptr, h2);

    // ---- atomic-free pool + head ----
    pool_partial<<<N_GRAPHS * 8, 256, 0, stream>>>(h2, gstart, partial);
    pool_head2<<<N_GRAPHS, 64, 0, stream>>>(partial, gstart, lin_w, lin_b,
                                            (float*)d_out);
}

// Round 17
// 266.707 us; speedup vs baseline: 1.3977x; 1.0109x over previous
//
#include <hip/hip_runtime.h>
#include <hip/hip_bf16.h>
#include <math.h>

#define N_NODES 50000
#define N_EDGES 1600000
#define N_GRAPHS 64
#define NB 391             // dst buckets of 128 nodes: b = dst >> 7
#define NBLK 1024          // partition chunks (R16's 256 -> 25-deep serial scatter tail)
#define CHUNK 1563         // edges per chunk (1024*1563 >= 1.6M, guarded)
#define ROW_STRIDE 80      // per-node adjacency capacity (multiple of 8)
#define SENT 50047         // sentinel node: al[SENT] = -1e30 -> exp(score) = 0

typedef unsigned int u32;
typedef __attribute__((ext_vector_type(8))) __bf16 bf16x8;
typedef __attribute__((ext_vector_type(4))) float f32x4;

__device__ __forceinline__ float bcf(u32 u) { return __builtin_bit_cast(float, u); }

template <int CTRL>
__device__ __forceinline__ float dpp_add(float v) {
    int r = __builtin_amdgcn_update_dpp(0, __builtin_bit_cast(int, v), CTRL, 0xF, 0xF, true);
    return v + __builtin_bit_cast(float, r);
}

__device__ __forceinline__ u32 pack_bf16x2(float lo, float hi) {
    unsigned short l = __builtin_bit_cast(unsigned short, __float2bfloat16(lo));
    unsigned short h = __builtin_bit_cast(unsigned short, __float2bfloat16(hi));
    return (u32)l | ((u32)h << 16);
}

// ---------------------------------------------------------------------------
// W -> MFMA-B-fragment layout, hi/lo residual split (rider blocks).
// ---------------------------------------------------------------------------
__device__ __forceinline__ void conv_w_dev(
    int K, const float* __restrict__ Wl, const float* __restrict__ Wr,
    u32* __restrict__ wfHi, u32* __restrict__ wfLo) {
    const int KO = K / 32;
    for (int idx = threadIdx.x; idx < KO * 8 * 64; idx += 256) {
        const int L = idx & 63;
        const int tile = idx >> 6;
        const int ko = tile >> 3, nt = tile & 7;
        const int c = nt * 16 + (L & 15);
        u32 hi[4], lo[4];
        float hv[8], lv[8];
#pragma unroll
        for (int i = 0; i < 8; ++i) {
            const int k = ko * 32 + (L >> 4) * 8 + i;
            const float wv = (c < 64) ? Wl[k * 64 + c] : Wr[k * 64 + (c - 64)];
            const __hip_bfloat16 h = __float2bfloat16(wv);
            hv[i] = wv;
            lv[i] = wv - __bfloat162float(h);
        }
#pragma unroll
        for (int i = 0; i < 4; ++i) {
            hi[i] = pack_bf16x2(hv[2 * i], hv[2 * i + 1]);
            lo[i] = pack_bf16x2(lv[2 * i], lv[2 * i + 1]);
        }
        *(uint4*)(wfHi + (size_t)idx * 4) = make_uint4(hi[0], hi[1], hi[2], hi[3]);
        *(uint4*)(wfLo + (size_t)idx * 4) = make_uint4(lo[0], lo[1], lo[2], lo[3]);
    }
}

// Blocks 0..NBLK-1: per-chunk dst-bucket histogram -> countsRM[chunk][bucket].
// Riders: NBLK -> conv_w L1, NBLK+1 -> conv_w L2, NBLK+2 -> graph starts.
__global__ __launch_bounds__(256) void count_kernel(
    const int* __restrict__ ei, int* __restrict__ countsRM,
    const float* __restrict__ Wl1, const float* __restrict__ Wr1,
    const float* __restrict__ Wl2, const float* __restrict__ Wr2,
    u32* __restrict__ wf1hi, u32* __restrict__ wf1lo,
    u32* __restrict__ wf2hi, u32* __restrict__ wf2lo,
    const int* __restrict__ batch, int* __restrict__ gstart) {
    if (blockIdx.x == NBLK) { conv_w_dev(128, Wl1, Wr1, wf1hi, wf1lo); return; }
    if (blockIdx.x == NBLK + 1) { conv_w_dev(64, Wl2, Wr2, wf2hi, wf2lo); return; }
    if (blockIdx.x == NBLK + 2) {
        const int g = threadIdx.x;
        if (g < N_GRAPHS) {
            int lo = 0, hi = N_NODES;
            while (lo < hi) {               // lower_bound(batch, g)
                const int mid = (lo + hi) >> 1;
                if (batch[mid] < g) lo = mid + 1; else hi = mid;
            }
            gstart[g] = lo;
        }
        if (threadIdx.x == 0) gstart[N_GRAPHS] = N_NODES;
        return;
    }
    __shared__ int h[NB];
    const int t = threadIdx.x;
    for (int k = t; k < NB; k += 256) h[k] = 0;
    __syncthreads();
    const int base = blockIdx.x * CHUNK;
    const int lim = min(base + CHUNK, N_EDGES);
    for (int e = base + t; e < lim; e += 256)
        atomicAdd(&h[ei[N_EDGES + e] >> 7], 1);
    __syncthreads();
    for (int k = t; k < NB; k += 256) countsRM[blockIdx.x * NB + k] = h[k];
}

// One block per bucket: exclusive scan over NBLK=1024 chunk counts
// (4 elements per thread + 256-wide block scan).
__global__ __launch_bounds__(256) void scan_bucket(
    const int* __restrict__ countsRM, int* __restrict__ scanT,
    int* __restrict__ totals) {
    __shared__ int tmp[256];
    const int b = blockIdx.x;
    const int t = threadIdx.x;
    int v[4];
    int s = 0;
#pragma unroll
    for (int i = 0; i < 4; ++i) {
        v[i] = countsRM[(t * 4 + i) * NB + b];
        s += v[i];
    }
    tmp[t] = s;
    __syncthreads();
    for (int off = 1; off < 256; off <<= 1) {
        int u = (t >= off) ? tmp[t - off] : 0;
        __syncthreads();
        tmp[t] += u;
        __syncthreads();
    }
    int run = tmp[t] - s;   // exclusive prefix for this thread's 4 chunks
#pragma unroll
    for (int i = 0; i < 4; ++i) {
        scanT[b * NBLK + t * 4 + i] = run;
        run += v[i];
    }
    if (t == 255) totals[b] = tmp[t];
}

__global__ __launch_bounds__(512) void scan_total(
    const int* __restrict__ totals, int* __restrict__ bucketBase,
    float* __restrict__ alb) {
    __shared__ int tmp[512];
    const int t = threadIdx.x;
    const int v0 = (t < NB) ? totals[t] : 0;
    tmp[t] = v0;
    __syncthreads();
    for (int off = 1; off < 512; off <<= 1) {
        int v = (t >= off) ? tmp[t - off] : 0;
        __syncthreads();
        tmp[t] += v;
        __syncthreads();
    }
    if (t < NB) bucketBase[t] = tmp[t] - v0;
    if (t == NB - 1) bucketBase[NB] = tmp[t];
    // L1-layout sentinel (indices 100094/100095; gemm writes only < 100000)
    if (t == 0) { alb[(size_t)SENT * 2] = -1e30f; alb[(size_t)SENT * 2 + 1] = -1e30f; }
}

// ---------------------------------------------------------------------------
// MFMA dense transform + fused radix scatter (blocks >= gemmBlocks; 1024
// light scatter blocks -> ~6-deep chains instead of R16's 25-deep tail).
// ---------------------------------------------------------------------------
template <int K, bool AF32, bool FUSE_SCATTER>
__global__ __launch_bounds__(256) void gemm_mfma(
    const float* __restrict__ xF, const u32* __restrict__ xB,
    const u32* __restrict__ wfHi, const u32* __restrict__ wfLo,
    const float* __restrict__ att,
    u32* __restrict__ xlb, float* __restrict__ xr,
    float* __restrict__ alb, float* __restrict__ arb,
    const int* __restrict__ ei, const int* __restrict__ scanT,
    const int* __restrict__ bb, int* __restrict__ sortedE, int gemmBlocks) {
    __shared__ float Ct[64][129];   // +1 pad: column reads conflict-free
    __shared__ float alq[64][4];
    const int t = threadIdx.x;
    if (FUSE_SCATTER && blockIdx.x >= gemmBlocks) {
        int* cursor = (int*)&Ct[0][0];
        const int b = blockIdx.x - gemmBlocks;
        for (int k = t; k < NB; k += 256)
            cursor[k] = bb[k] + scanT[k * NBLK + b];
        __syncthreads();
        const int base = b * CHUNK;
        const int lim = min(base + CHUNK, N_EDGES);
        for (int e = base + t; e < lim; e += 256) {
            const int s = ei[e];
            const int d = ei[N_EDGES + e];
            const int idx = atomicAdd(&cursor[d >> 7], 1);   // LDS atomic
            sortedE[idx] = (s << 7) | (d & 127);
        }
        return;
    }
    const int KO = K / 32;
    const int lane = t & 63;
    const int w = __builtin_amdgcn_readfirstlane(t >> 6);
    const int quad = lane >> 4;
    const int m16 = lane & 15;
    const int base = blockIdx.x * 64;
    const int arow = base + w * 16 + m16;
    const int rowc = arow < N_NODES ? arow : N_NODES - 1;   // clamp (safe loads)

    f32x4 acc[8];
    const f32x4 zz = {0.f, 0.f, 0.f, 0.f};
#pragma unroll
    for (int i = 0; i < 8; ++i) acc[i] = zz;

#pragma unroll
    for (int ko = 0; ko < KO; ++ko) {
        bf16x8 af;
        if (AF32) {
            const float* ap = xF + (size_t)rowc * K + ko * 32 + quad * 8;
            const float4 a0 = *(const float4*)ap;
            const float4 a1 = *(const float4*)(ap + 4);
            af = __builtin_bit_cast(bf16x8, make_uint4(
                pack_bf16x2(a0.x, a0.y), pack_bf16x2(a0.z, a0.w),
                pack_bf16x2(a1.x, a1.y), pack_bf16x2(a1.z, a1.w)));
        } else {
            af = __builtin_bit_cast(bf16x8,
                *(const uint4*)(xB + ((size_t)rowc * K + ko * 32 + quad * 8) / 2));
        }
#pragma unroll
        for (int nt = 0; nt < 8; ++nt) {
            const uint4 bh = *(const uint4*)(wfHi + (size_t)((ko * 8 + nt) * 64 + lane) * 4);
            acc[nt] = __builtin_amdgcn_mfma_f32_16x16x32_bf16(
                af, __builtin_bit_cast(bf16x8, bh), acc[nt], 0, 0, 0);
        }
#pragma unroll
        for (int nt = 0; nt < 8; ++nt) {
            const uint4 bl = *(const uint4*)(wfLo + (size_t)((ko * 8 + nt) * 64 + lane) * 4);
            acc[nt] = __builtin_amdgcn_mfma_f32_16x16x32_bf16(
                af, __builtin_bit_cast(bf16x8, bl), acc[nt], 0, 0, 0);
        }
    }
    // C/D layout: col = lane&15, row = quad*4 + reg   [verified mapping]
#pragma unroll
    for (int nt = 0; nt < 8; ++nt)
#pragma unroll
        for (int r = 0; r < 4; ++r)
            Ct[w * 16 + quad * 4 + r][nt * 16 + m16] = acc[nt][r];
    __syncthreads();

    const int node = t & 63;
    const int q = t >> 6;          // quarter: 0,1 -> xl cols; 2,3 -> xr cols
    const int n = base + node;
    float av = 0.f;
    if (n < N_NODES) {
        if (q < 2) {
            u32 pk[16];
#pragma unroll
            for (int j = 0; j < 32; j += 2) {
                const float v0 = Ct[node][q * 32 + j];
                const float v1 = Ct[node][q * 32 + j + 1];
                av = fmaf(att[q * 32 + j], v0, av);
                av = fmaf(att[q * 32 + j + 1], v1, av);
                pk[j >> 1] = pack_bf16x2(v0, v1);
            }
            uint4* dst = (uint4*)(xlb + (size_t)n * 32 + q * 16);
#pragma unroll
            for (int j = 0; j < 4; ++j)
                dst[j] = make_uint4(pk[j * 4], pk[j * 4 + 1], pk[j * 4 + 2], pk[j * 4 + 3]);
        } else {
            const int cb = (q - 2) * 32;
#pragma unroll
            for (int j = 0; j < 32; j += 4) {
                float4 v = {Ct[node][64 + cb + j], Ct[node][64 + cb + j + 1],
                            Ct[node][64 + cb + j + 2], Ct[node][64 + cb + j + 3]};
                av = fmaf(att[cb + j], v.x, av);
                av = fmaf(att[cb + j + 1], v.y, av);
                av = fmaf(att[cb + j + 2], v.z, av);
                av = fmaf(att[cb + j + 3], v.w, av);
                *(float4*)(xr + (size_t)n * 64 + cb + j) = v;
            }
        }
    }
    alq[node][q] = av;
    __syncthreads();
    if (t < 64 && base + t < N_NODES) {
        const int nn = base + t;
        if (K == 128) {
            alb[(size_t)nn * 2] = alq[t][0];
            alb[(size_t)nn * 2 + 1] = alq[t][1];
        } else {
            alb[nn] = alq[t][0] + alq[t][1];   // pre-summed for L2
        }
        arb[(size_t)nn * 2] = alq[t][2];
        arb[(size_t)nn * 2 + 1] = alq[t][3];
    }
    if (K == 64 && blockIdx.x == 0 && t == 0) alb[SENT] = -1e30f;   // L2 sentinel
}

// Expand: self-loop pre-seeded as entry 0; rows padded to x8 with SENT.
__global__ __launch_bounds__(256) void expand_kernel(
    const int* __restrict__ bucketBase, const int* __restrict__ sortedE,
    int* __restrict__ deg, int* __restrict__ rows) {
    __shared__ int ldeg[128];
    const int b = blockIdx.x;
    const int t = threadIdx.x;
    const int node_base = b * 128;
    if (t < 128) {
        const int n = node_base + t;
        ldeg[t] = 1;
        if (n < N_NODES) rows[(size_t)n * ROW_STRIDE] = n;   // self loop
    }
    __syncthreads();
    const int beg = bucketBase[b];
    const int end = bucketBase[b + 1];
    for (int i = beg + t; i < end; i += 256) {
        const int en = sortedE[i];
        const int ld = en & 127;
        const int pos = atomicAdd(&ldeg[ld], 1);
        if (pos < ROW_STRIDE) rows[(size_t)(node_base + ld) * ROW_STRIDE + pos] = en >> 7;
    }
    __syncthreads();
    if (t < 128) {
        const int n = node_base + t;
        if (n < N_NODES) {
            int c = ldeg[t];
            c = c < ROW_STRIDE ? c : ROW_STRIDE;
            const int cp = (c + 7) & ~7;
            for (int j = c; j < cp; ++j) rows[(size_t)n * ROW_STRIDE + j] = SENT;
            deg[n] = cp;
        }
    }
}

// ---------------------------------------------------------------------------
// Node-centric GATv2: one wave per dst node, 8 lanes/edge (8 bf16 ch/lane),
// 8 edges per wave-instruction. score = 0.6*(al_s + ar_d) + 0.4*sum att|u|.
// ---------------------------------------------------------------------------
template <bool L1>
__global__ __launch_bounds__(256) void node_layer(
    const int* __restrict__ deg, const int* __restrict__ rows,
    const u32* __restrict__ xlb, const float* __restrict__ xr,
    const float* __restrict__ alb, const float* __restrict__ arb,
    const float* __restrict__ att, const float* __restrict__ bias,
    u32* __restrict__ houtB, float* __restrict__ houtF) {
    const int n = (blockIdx.x * 256 + threadIdx.x) >> 6;
    const int lane = threadIdx.x & 63;
    const int sub = lane & 7;        // channel octet: ch = sub*8 .. +7
    const int g = lane >> 3;         // edge slot 0..7
    const float4 xra = *(const float4*)(xr + (size_t)n * 64 + sub * 8);
    const float4 xrb = *(const float4*)(xr + (size_t)n * 64 + sub * 8 + 4);
    const float4 ata = *(const float4*)(att + sub * 8);
    const float4 atb = *(const float4*)(att + sub * 8 + 4);
    const float2 ar2 = *(const float2*)(arb + (size_t)n * 2);
    const float based = 0.6f * (L1 ? ((sub & 4) ? ar2.y : ar2.x) : (ar2.x + ar2.y));

    float c0 = 0.f, c1 = 0.f, c2 = 0.f, c3 = 0.f;
    float c4 = 0.f, c5 = 0.f, c6 = 0.f, c7 = 0.f;
    float ssum = 0.f;
    const int cp = __builtin_amdgcn_readfirstlane(deg[n]);
    const int* __restrict__ row = rows + (size_t)n * ROW_STRIDE;
    for (int i = 0; i < cp; i += 8) {
        const int s = row[i + g];
        const float als = L1 ? alb[(size_t)s * 2 + ((sub >> 2) & 1)] : alb[s];
        const uint4 r4 = *(const uint4*)(xlb + (size_t)s * 32 + sub * 4);
        const float a0 = bcf(r4.x << 16), a1 = bcf(r4.x & 0xFFFF0000u);
        const float a2f = bcf(r4.y << 16), a3 = bcf(r4.y & 0xFFFF0000u);
        const float a4 = bcf(r4.z << 16), a5 = bcf(r4.z & 0xFFFF0000u);
        const float a6 = bcf(r4.w << 16), a7 = bcf(r4.w & 0xFFFF0000u);
        float v = ata.x * fabsf(a0 + xra.x);
        v = fmaf(ata.y, fabsf(a1 + xra.y), v);
        v = fmaf(ata.z, fabsf(a2f + xra.z), v);
        v = fmaf(ata.w, fabsf(a3 + xra.w), v);
        v = fmaf(atb.x, fabsf(a4 + xrb.x), v);
        v = fmaf(atb.y, fabsf(a5 + xrb.y), v);
        v = fmaf(atb.z, fabsf(a6 + xrb.z), v);
        v = fmaf(atb.w, fabsf(a7 + xrb.w), v);
        v = dpp_add<0xB1>(v);            // xor 1
        v = dpp_add<0x4E>(v);            // xor 2  (L1: 4-lane head reduce done)
        if (!L1) v = dpp_add<0x141>(v);  // row_half_mirror: 8-lane reduce
        const float ev = __expf(fmaf(0.6f, als, fmaf(0.4f, v, based)));
        c0 = fmaf(ev, a0, c0); c1 = fmaf(ev, a1, c1);
        c2 = fmaf(ev, a2f, c2); c3 = fmaf(ev, a3, c3);
        c4 = fmaf(ev, a4, c4); c5 = fmaf(ev, a5, c5);
        c6 = fmaf(ev, a6, c6); c7 = fmaf(ev, a7, c7);
        ssum += ev;
    }
#define XRED(x) x += __shfl_xor(x, 8); x += __shfl_xor(x, 16); x += __shfl_xor(x, 32);
    XRED(c0) XRED(c1) XRED(c2) XRED(c3) XRED(c4) XRED(c5) XRED(c6) XRED(c7) XRED(ssum)
#undef XRED
    if (g == 0) {
        const float inv = 1.f / (ssum + 1e-16f);
        const float4 ba = *(const float4*)(bias + sub * 8);
        const float4 bb = *(const float4*)(bias + sub * 8 + 4);
        float o[8] = {c0 * inv + ba.x, c1 * inv + ba.y, c2 * inv + ba.z, c3 * inv + ba.w,
                      c4 * inv + bb.x, c5 * inv + bb.y, c6 * inv + bb.z, c7 * inv + bb.w};
#pragma unroll
        for (int j = 0; j < 8; ++j) o[j] = o[j] > 0.f ? o[j] : expm1f(o[j]);
        if (L1) {
            *(uint4*)(houtB + (size_t)n * 32 + sub * 4) = make_uint4(
                pack_bf16x2(o[0], o[1]), pack_bf16x2(o[2], o[3]),
                pack_bf16x2(o[4], o[5]), pack_bf16x2(o[6], o[7]));
        } else {
            *(float4*)(houtF + (size_t)n * 64 + sub * 8) = make_float4(o[0], o[1], o[2], o[3]);
            *(float4*)(houtF + (size_t)n * 64 + sub * 8 + 4) = make_float4(o[4], o[5], o[6], o[7]);
        }
    }
}

// ---------------------------------------------------------------------------
// Atomic-free pooling, phase A: block = (graph g, strip s of 8).
// ---------------------------------------------------------------------------
__global__ __launch_bounds__(256) void pool_partial(
    const float* __restrict__ h2, const int* __restrict__ gstart,
    float* __restrict__ partial) {
    __shared__ float ps[4][64];
    const int gs = blockIdx.x;
    const int g = gs >> 3, s = gs & 7;
    const int t = threadIdx.x;
    const int lane = t & 63;
    const int w = t >> 6;
    const int beg = gstart[g], end = gstart[g + 1];
    const int len = end - beg;
    const int chunk = (len + 7) >> 3;
    const int lo = beg + s * chunk;
    const int hi = min(lo + chunk, end);
    float a0 = 0.f, a1 = 0.f;
    int n = lo + w;
    for (; n + 4 < hi; n += 8) {
        a0 += h2[(size_t)n * 64 + lane];
        a1 += h2[(size_t)(n + 4) * 64 + lane];
    }
    if (n < hi) a0 += h2[(size_t)n * 64 + lane];
    ps[w][lane] = a0 + a1;
    __syncthreads();
    if (t < 64)
        partial[(size_t)gs * 64 + t] = ps[0][t] + ps[1][t] + ps[2][t] + ps[3][t];
}

// Phase B + head: one wave per graph; no atomics, no fences.
__global__ __launch_bounds__(64) void pool_head2(
    const float* __restrict__ partial, const int* __restrict__ gstart,
    const float* __restrict__ lin_w, const float* __restrict__ lin_b,
    float* __restrict__ out) {
    const int g = blockIdx.x;
    const int t = threadIdx.x;
    float sum = 0.f;
#pragma unroll
    for (int s = 0; s < 8; ++s) sum += partial[(size_t)(g * 8 + s) * 64 + t];
    float c = (float)(gstart[g + 1] - gstart[g]);
    c = c > 1.f ? c : 1.f;
    const float m = sum / c;
    float v0 = m * lin_w[t * 2];
    float v1 = m * lin_w[t * 2 + 1];
#pragma unroll
    for (int off = 1; off < 64; off <<= 1) {
        v0 += __shfl_xor(v0, off);
        v1 += __shfl_xor(v1, off);
    }
    if (t == 0) {
        out[g * 2] = v0 + lin_b[0];
        out[g * 2 + 1] = v1 + lin_b[1];
    }
}

extern "C" void kernel_launch(void* const* d_in, const int* in_sizes, int n_in,
                              void* d_out, int out_size, void* d_ws, size_t ws_size,
                              hipStream_t stream) {
    const float* x     = (const float*)d_in[0];
    const int*   ei    = (const int*)d_in[1];
    const int*   batch = (const int*)d_in[2];
    const float* Wl1   = (const float*)d_in[3];
    const float* Wr1   = (const float*)d_in[4];
    const float* att1  = (const float*)d_in[5];
    const float* b1    = (const float*)d_in[6];
    const float* Wl2   = (const float*)d_in[7];
    const float* Wr2   = (const float*)d_in[8];
    const float* att2  = (const float*)d_in[9];
    const float* b2    = (const float*)d_in[10];
    const float* lin_w = (const float*)d_in[11];
    const float* lin_b = (const float*)d_in[12];

    float* ws = (float*)d_ws;     // offsets in dwords
    u32*   h1b      = (u32*)ws;                    //  1,601,536 (50048*32)
    u32*   xlb      = (u32*)(ws + 1601536);        //  1,601,536
    float* xr       = ws + 3203072;                //  3,203,072 (50048*64)
    float* h2       = ws + 6406144;                //  3,203,072
    float* alb      = ws + 9609216;                //    100,096
    float* arb      = ws + 9709312;                //    100,096
    int*   rows     = (int*)(ws + 9809408);        //  4,003,840 (50048*80)
    int*   deg      = (int*)(ws + 13813248);       //     50,048
    int*   countsRM = (int*)(ws + 13863296);       //    400,384 (1024*391)
    int*   scanT    = (int*)(ws + 14263680);       //    400,384 (391*1024)
    int*   totals   = (int*)(ws + 14664064);       //        512
    int*   bb       = (int*)(ws + 14664576);       //        512
    int*   sortedE  = (int*)(ws + 14665088);       //  1,600,000
    u32*   wf1hi    = (u32*)(ws + 16265088);       //      8,192
    u32*   wf1lo    = (u32*)(ws + 16273280);       //      8,192
    u32*   wf2hi    = (u32*)(ws + 16281472);       //      4,096
    u32*   wf2lo    = (u32*)(ws + 16285568);       //      4,096
    int*   gstart   = (int*)(ws + 16289664);       //        128
    float* partial  = ws + 16289792;               //     32,768 (512*64)
    // total ~16.3M dwords ~= 65 MB (ws is 256 MiB); no global atomics -> no memset.

    const int gblocks = (N_NODES + 63) / 64;   // 782

    // ---- build prologue: histogram + riders (W-frags, graph starts) ----
    count_kernel<<<NBLK + 3, 256, 0, stream>>>(
        ei, countsRM, Wl1, Wr1, Wl2, Wr2, wf1hi, wf1lo, wf2hi, wf2lo,
        batch, gstart);
    scan_bucket<<<NB, 256, 0, stream>>>(countsRM, scanT, totals);
    scan_total<<<1, 512, 0, stream>>>(totals, bb, alb);

    // ---- layer-1 MFMA gemm (direct f32 x) fused with 1024-way scatter ----
    gemm_mfma<128, true, true><<<gblocks + NBLK, 256, 0, stream>>>(
        x, nullptr, wf1hi, wf1lo, att1, xlb, xr, alb, arb,
        ei, scanT, bb, sortedE, gblocks);

    expand_kernel<<<NB, 256, 0, stream>>>(bb, sortedE, deg, rows);

    // ---- layer 1 node pass (emits packed bf16 h1) ----
    node_layer<true><<<N_NODES / 4, 256, 0, stream>>>(
        deg, rows, xlb, xr, alb, arb, att1, b1, h1b, nullptr);

    // ---- layer 2 ----
    gemm_mfma<64, false, false><<<gblocks, 256, 0, stream>>>(
        nullptr, h1b, wf2hi, wf2lo, att2, xlb, xr, alb, arb,
        nullptr, nullptr, nullptr, nullptr, gblocks);
    node_layer<false><<<N_NODES / 4, 256, 0, stream>>>(
        deg, rows, xlb, xr, alb, arb, att2, b2, nullptr, h2);

    // ---- atomic-free pool + head ----
    pool_partial<<<N_GRAPHS * 8, 256, 0, stream>>>(h2, gstart, partial);
    pool_head2<<<N_GRAPHS, 64, 0, stream>>>(partial, gstart, lin_w, lin_b,
                                            (float*)d_out);
}